// Round 1
// baseline (136.985 us; speedup 1.0000x reference)
//
#include <hip/hip_runtime.h>
#include <math.h>

#define NN 8192
#define CC 256
#define LOG2N 13

// ---------------- ws layout (floats) ----------------
// aggP : [64][256]       offset 0       (agg partial sums per row-chunk)
// zrP  : [6][4][256]     offset 16384   (Z/R matvec partials: m*4+q)
// zvec : [256]           offset 22528
// rsvec: [256]           offset 22784   (h_head * R)
// htP  : [2][4][256]     offset 23040   (H_tilde matvec partials)
#define WS_AGGP  0
#define WS_ZRP   16384
#define WS_ZVEC  22528
#define WS_RSVEC 22784
#define WS_HTP   23040

// A: agg partials. 64 blocks x 256 threads; block b handles rows [b*128, b*128+128)
__global__ void k_agg_partial(const float* __restrict__ E, const float* __restrict__ H,
                              const int* __restrict__ dh, const int* __restrict__ dt,
                              float* __restrict__ aggP) {
    __shared__ float e_sh[128];
    const int head = dh[0], tail = dt[0];
    const int i0 = blockIdx.x * 128;
    const int t = threadIdx.x;
    if (t < 128) {
        const int i = i0 + t;
        float e = 0.5f * E[(size_t)head * NN + i] + 0.5f * E[(size_t)tail * NN + i];
        if (i == tail) e += 0.5f;
        e_sh[t] = e;
    }
    __syncthreads();
    float acc = 0.f;
    for (int k = 0; k < 128; ++k)
        acc += e_sh[k] * H[(size_t)(i0 + k) * CC + t];
    aggP[blockIdx.x * CC + t] = acc;
}

// B: Z/R matvec partials. 24 blocks (m = 0..5, q = 0..3) x 256 threads.
// m: 0=W_x_z(X) 1=W_h_z(h) 2=conv_z(agg) 3=W_x_r(X) 4=W_h_r(h) 5=conv_r(agg)
__global__ void k_zr_partial(const float* __restrict__ X, const float* __restrict__ H,
                             const int* __restrict__ dh,
                             const float* __restrict__ Wxz, const float* __restrict__ Whz,
                             const float* __restrict__ Cz,  const float* __restrict__ Wxr,
                             const float* __restrict__ Whr, const float* __restrict__ Cr,
                             const float* __restrict__ aggP, float* __restrict__ zrP) {
    __shared__ float v_sh[64];
    const int m = blockIdx.x >> 2, q = blockIdx.x & 3;
    const int t = threadIdx.x;
    const int head = dh[0];
    const float* W;
    switch (m) {
        case 0: W = Wxz; break; case 1: W = Whz; break; case 2: W = Cz; break;
        case 3: W = Wxr; break; case 4: W = Whr; break; default: W = Cr; break;
    }
    if (t < 64) {
        const int k = q * 64 + t;
        float v;
        if (m == 0 || m == 3)      v = X[k];
        else if (m == 1 || m == 4) v = H[(size_t)head * CC + k];
        else { v = 0.f; for (int b = 0; b < 64; ++b) v += aggP[b * CC + k]; }
        v_sh[t] = v;
    }
    __syncthreads();
    float acc = 0.f;
    for (int kk = 0; kk < 64; ++kk)
        acc += v_sh[kk] * W[(size_t)(q * 64 + kk) * CC + t];
    zrP[(m * 4 + q) * CC + t] = acc;
}

// C1: reduce Z/R partials, sigmoid, produce zvec and rsvec = h_head * R. 1 block x 256.
__global__ void k_zr_finish(const float* __restrict__ H, const int* __restrict__ dh,
                            const float* __restrict__ bz, const float* __restrict__ br,
                            const float* __restrict__ zrP,
                            float* __restrict__ zvec, float* __restrict__ rsvec) {
    const int c = threadIdx.x;
    const int head = dh[0];
    float sz = bz[c], sr = br[c];
    for (int p = 0; p < 12; ++p)  sz += zrP[p * CC + c];
    for (int p = 12; p < 24; ++p) sr += zrP[p * CC + c];
    const float z = 1.f / (1.f + expf(-sz));
    const float r = 1.f / (1.f + expf(-sr));
    zvec[c] = z;
    rsvec[c] = H[(size_t)head * CC + c] * r;
}

// C2: H_tilde matvec partials. 8 blocks (m = 0..1, q = 0..3) x 256 threads.
__global__ void k_ht_partial(const float* __restrict__ X, const float* __restrict__ rsvec,
                             const float* __restrict__ Wxh, const float* __restrict__ Whh,
                             float* __restrict__ htP) {
    __shared__ float v_sh[64];
    const int m = blockIdx.x >> 2, q = blockIdx.x & 3;
    const int t = threadIdx.x;
    const float* W = m ? Whh : Wxh;
    const float* v = m ? rsvec : X;
    if (t < 64) v_sh[t] = v[q * 64 + t];
    __syncthreads();
    float acc = 0.f;
    for (int kk = 0; kk < 64; ++kk)
        acc += v_sh[kk] * W[(size_t)(q * 64 + kk) * CC + t];
    htP[(m * 4 + q) * CC + t] = acc;
}

// E: big memory-bound kernel — E_new (0.5*E with special head row) + bulk H copy.
__global__ void k_big(const float* __restrict__ E, const float* __restrict__ H,
                      const int* __restrict__ dh, const int* __restrict__ dt,
                      float* __restrict__ out) {
    const int head = dh[0], tail = dt[0];
    const size_t nn = (size_t)NN * NN;
    const size_t total4 = (nn + (size_t)NN * CC) >> 2;
    const size_t stride = (size_t)gridDim.x * blockDim.x;
    for (size_t idx = (size_t)blockIdx.x * blockDim.x + threadIdx.x; idx < total4; idx += stride) {
        const size_t e = idx << 2;
        if (e < nn) {
            const float4 v = *(const float4*)(E + e);
            float4 o = make_float4(0.5f * v.x, 0.5f * v.y, 0.5f * v.z, 0.5f * v.w);
            const int i = (int)(e >> LOG2N);
            if (i == head) {
                const int j = (int)(e & (NN - 1));
                const float4 w = *(const float4*)(E + (size_t)tail * NN + j);
                o.x += 0.5f * w.x; o.y += 0.5f * w.y;
                o.z += 0.5f * w.z; o.w += 0.5f * w.w;
                if (tail >= j && tail < j + 4) ((float*)&o)[tail - j] += 0.5f;
            }
            *(float4*)(out + e) = o;
        } else {
            const size_t t = e - nn;
            *(float4*)(out + nn + t) = *(const float4*)(H + t);
        }
    }
}

// D: final head row of H_new. 1 block x 256 threads. Must run after k_big.
__global__ void k_final_row(const float* __restrict__ H, const int* __restrict__ dh,
                            const float* __restrict__ bh, const float* __restrict__ htP,
                            const float* __restrict__ zvec, float* __restrict__ out) {
    const int c = threadIdx.x;
    const int head = dh[0];
    float s = bh[c];
    for (int p = 0; p < 8; ++p) s += htP[p * CC + c];
    const float ht = tanhf(s);
    const float z = zvec[c];
    const float h = H[(size_t)head * CC + c];
    out[(size_t)NN * NN + (size_t)head * CC + c] = z * h + (1.f - z) * ht;
}

extern "C" void kernel_launch(void* const* d_in, const int* in_sizes, int n_in,
                              void* d_out, int out_size, void* d_ws, size_t ws_size,
                              hipStream_t stream) {
    const float* X    = (const float*)d_in[0];
    const int*   dh   = (const int*)d_in[1];
    const int*   dt   = (const int*)d_in[2];
    const float* E    = (const float*)d_in[3];
    const float* H    = (const float*)d_in[4];
    const float* Wxz  = (const float*)d_in[5];
    const float* Whz  = (const float*)d_in[6];
    const float* Cz   = (const float*)d_in[7];
    const float* bz   = (const float*)d_in[8];
    const float* Wxr  = (const float*)d_in[9];
    const float* Whr  = (const float*)d_in[10];
    const float* Cr   = (const float*)d_in[11];
    const float* br   = (const float*)d_in[12];
    const float* Wxh  = (const float*)d_in[13];
    const float* Whh  = (const float*)d_in[14];
    const float* bh   = (const float*)d_in[15];
    float* out = (float*)d_out;
    float* ws  = (float*)d_ws;

    float* aggP  = ws + WS_AGGP;
    float* zrP   = ws + WS_ZRP;
    float* zvec  = ws + WS_ZVEC;
    float* rsvec = ws + WS_RSVEC;
    float* htP   = ws + WS_HTP;

    k_agg_partial<<<64, 256, 0, stream>>>(E, H, dh, dt, aggP);
    k_zr_partial<<<24, 256, 0, stream>>>(X, H, dh, Wxz, Whz, Cz, Wxr, Whr, Cr, aggP, zrP);
    k_zr_finish<<<1, 256, 0, stream>>>(H, dh, bz, br, zrP, zvec, rsvec);
    k_ht_partial<<<8, 256, 0, stream>>>(X, rsvec, Wxh, Whh, htP);
    k_big<<<2048, 256, 0, stream>>>(E, H, dh, dt, out);
    k_final_row<<<1, 256, 0, stream>>>(H, dh, bh, htP, zvec, out);
}

// Round 2
// 113.939 us; speedup vs baseline: 1.2023x; 1.2023x over previous
//
#include <hip/hip_runtime.h>
#include <math.h>

#define NN 8192
#define CC 256
#define LOG2N 13

typedef float f32x4 __attribute__((ext_vector_type(4)));

// ---------------- ws layout (floats) ----------------
// aggP : [128][256]   offset 0      (agg partial sums per 64-row chunk)
// zrP  : [6][4][256]  offset 32768  (Z/R matvec partials: m*4+q)
// htP  : [2][4][256]  offset 38912  (H_tilde matvec partials)
#define WS_AGGP 0
#define WS_ZRP  32768
#define WS_HTP  38912

// A: agg partials. 128 blocks x 256 threads; block b handles rows [b*64, b*64+64).
// e_new_head[i] = 0.5*E[head,i] + (head!=tail ? 0.5*E[tail,i] : 0) + (i==tail ? 0.5 : 0)
__global__ void k_agg_partial(const float* __restrict__ E, const float* __restrict__ H,
                              const int* __restrict__ dh, const int* __restrict__ dt,
                              float* __restrict__ aggP) {
    __shared__ float e_sh[64];
    const int head = dh[0], tail = dt[0];
    const int i0 = blockIdx.x * 64;
    const int t = threadIdx.x;
    if (t < 64) {
        const int i = i0 + t;
        float e = 0.5f * E[(size_t)head * NN + i];
        if (head != tail) e += 0.5f * E[(size_t)tail * NN + i];
        if (i == tail) e += 0.5f;
        e_sh[t] = e;
    }
    __syncthreads();
    float acc = 0.f;
    for (int k = 0; k < 64; ++k)
        acc += e_sh[k] * H[(size_t)(i0 + k) * CC + t];
    aggP[blockIdx.x * CC + t] = acc;
}

// B: Z/R matvec partials. 24 blocks (m = 0..5, q = 0..3) x 256 threads.
// m: 0=W_x_z(X) 1=W_h_z(h) 2=conv_z(agg) 3=W_x_r(X) 4=W_h_r(h) 5=conv_r(agg)
__global__ void k_zr_partial(const float* __restrict__ X, const float* __restrict__ H,
                             const int* __restrict__ dh,
                             const float* __restrict__ Wxz, const float* __restrict__ Whz,
                             const float* __restrict__ Cz,  const float* __restrict__ Wxr,
                             const float* __restrict__ Whr, const float* __restrict__ Cr,
                             const float* __restrict__ aggP, float* __restrict__ zrP) {
    __shared__ float v_sh[64];
    const int m = blockIdx.x >> 2, q = blockIdx.x & 3;
    const int t = threadIdx.x;
    const int head = dh[0];
    const float* W;
    switch (m) {
        case 0: W = Wxz; break; case 1: W = Whz; break; case 2: W = Cz; break;
        case 3: W = Wxr; break; case 4: W = Whr; break; default: W = Cr; break;
    }
    if (t < 64) {
        const int k = q * 64 + t;
        float v;
        if (m == 0 || m == 3)      v = X[k];
        else if (m == 1 || m == 4) v = H[(size_t)head * CC + k];
        else { v = 0.f; for (int b = 0; b < 128; ++b) v += aggP[b * CC + k]; }
        v_sh[t] = v;
    }
    __syncthreads();
    float acc = 0.f;
    for (int kk = 0; kk < 64; ++kk)
        acc += v_sh[kk] * W[(size_t)(q * 64 + kk) * CC + t];
    zrP[(m * 4 + q) * CC + t] = acc;
}

// C: H_tilde matvec partials; rsvec = h_head * sigmoid(R) computed inline (redundantly
// per block from the R partials — 12 adds + 1 exp per element, trivial).
// 8 blocks (m = 0..1, q = 0..3) x 256 threads. m: 0=W_x_h(X) 1=W_h_h(rsvec)
__global__ void k_ht_partial(const float* __restrict__ X, const float* __restrict__ H,
                             const int* __restrict__ dh, const float* __restrict__ br,
                             const float* __restrict__ zrP,
                             const float* __restrict__ Wxh, const float* __restrict__ Whh,
                             float* __restrict__ htP) {
    __shared__ float v_sh[64];
    const int m = blockIdx.x >> 2, q = blockIdx.x & 3;
    const int t = threadIdx.x;
    if (t < 64) {
        const int k = q * 64 + t;
        if (m == 0) {
            v_sh[t] = X[k];
        } else {
            float sr = br[k];
            for (int p = 12; p < 24; ++p) sr += zrP[p * CC + k];
            const float r = 1.f / (1.f + expf(-sr));
            v_sh[t] = H[(size_t)dh[0] * CC + k] * r;
        }
    }
    __syncthreads();
    const float* W = m ? Whh : Wxh;
    float acc = 0.f;
    for (int kk = 0; kk < 64; ++kk)
        acc += v_sh[kk] * W[(size_t)(q * 64 + kk) * CC + t];
    htP[(m * 4 + q) * CC + t] = acc;
}

// D: big memory-bound kernel — E_new + bulk H copy (head row skipped) with
// nontemporal streaming; the last block also computes the final head row of H_new.
__global__ void __launch_bounds__(256) k_big(
        const float* __restrict__ E, const float* __restrict__ H,
        const int* __restrict__ dh, const int* __restrict__ dt,
        const float* __restrict__ bz, const float* __restrict__ bh,
        const float* __restrict__ zrP, const float* __restrict__ htP,
        float* __restrict__ out) {
    const int head = dh[0], tail = dt[0];
    const size_t nn = (size_t)NN * NN;

    if (blockIdx.x == gridDim.x - 1) {
        // final head row: z*h + (1-z)*tanh(Wxh@X + Whh@rsvec + bh)
        const int c = threadIdx.x;
        float sz = bz[c];
        for (int p = 0; p < 12; ++p) sz += zrP[p * CC + c];
        const float z = 1.f / (1.f + expf(-sz));
        float s = bh[c];
        for (int p = 0; p < 8; ++p) s += htP[p * CC + c];
        const float ht = tanhf(s);
        const float h = H[(size_t)head * CC + c];
        out[nn + (size_t)head * CC + c] = z * h + (1.f - z) * ht;
    }

    const size_t total4 = (nn + (size_t)NN * CC) >> 2;
    const size_t stride = (size_t)gridDim.x * blockDim.x;
    for (size_t idx = (size_t)blockIdx.x * blockDim.x + threadIdx.x; idx < total4; idx += stride) {
        const size_t e = idx << 2;
        if (e < nn) {
            f32x4 v = __builtin_nontemporal_load((const f32x4*)(E + e));
            f32x4 o = v * 0.5f;
            const int i = (int)(e >> LOG2N);
            if (i == head) {
                const int j = (int)(e & (NN - 1));
                if (head != tail) {
                    const f32x4 w = *(const f32x4*)(E + (size_t)tail * NN + j);
                    o += w * 0.5f;
                }
                if (tail >= j && tail < j + 4) o[tail - j] += 0.5f;
            }
            __builtin_nontemporal_store(o, (f32x4*)(out + e));
        } else {
            const size_t t = e - nn;
            const int row = (int)(t >> 8);
            if (row != head) {
                const f32x4 hv = __builtin_nontemporal_load((const f32x4*)(H + t));
                __builtin_nontemporal_store(hv, (f32x4*)(out + nn + t));
            }
        }
    }
}

extern "C" void kernel_launch(void* const* d_in, const int* in_sizes, int n_in,
                              void* d_out, int out_size, void* d_ws, size_t ws_size,
                              hipStream_t stream) {
    const float* X    = (const float*)d_in[0];
    const int*   dh   = (const int*)d_in[1];
    const int*   dt   = (const int*)d_in[2];
    const float* E    = (const float*)d_in[3];
    const float* H    = (const float*)d_in[4];
    const float* Wxz  = (const float*)d_in[5];
    const float* Whz  = (const float*)d_in[6];
    const float* Cz   = (const float*)d_in[7];
    const float* bz   = (const float*)d_in[8];
    const float* Wxr  = (const float*)d_in[9];
    const float* Whr  = (const float*)d_in[10];
    const float* Cr   = (const float*)d_in[11];
    const float* br   = (const float*)d_in[12];
    const float* Wxh  = (const float*)d_in[13];
    const float* Whh  = (const float*)d_in[14];
    const float* bh   = (const float*)d_in[15];
    float* out = (float*)d_out;
    float* ws  = (float*)d_ws;

    float* aggP = ws + WS_AGGP;
    float* zrP  = ws + WS_ZRP;
    float* htP  = ws + WS_HTP;

    k_agg_partial<<<128, 256, 0, stream>>>(E, H, dh, dt, aggP);
    k_zr_partial<<<24, 256, 0, stream>>>(X, H, dh, Wxz, Whz, Cz, Wxr, Whr, Cr, aggP, zrP);
    k_ht_partial<<<8, 256, 0, stream>>>(X, H, dh, br, zrP, Wxh, Whh, htP);
    k_big<<<2048, 256, 0, stream>>>(E, H, dh, dt, bz, bh, zrP, htP, out);
}